// Round 1
// baseline (191.702 us; speedup 1.0000x reference)
//
#include <hip/hip_runtime.h>

#define N_ENT 100000
#define EMBED_DIM 128
#define SPARSE_THRESHOLD 5

// One 128-thread block per output row. path_rows is sorted, so each row's
// edge segment is found by binary search (block-uniform -> scalar loads).
// Rows with degree > SPARSE_THRESHOLD are exactly zero in the reference
// (mask applied after SpMM), so we skip their aggregation entirely (~85%).
__global__ __launch_bounds__(EMBED_DIM) void path_agg_kernel(
    const float* __restrict__ embeds,     // [N_ENT, 128]
    const int*   __restrict__ degrees,    // [N_ENT]
    const int*   __restrict__ rows,       // [E], sorted ascending
    const int*   __restrict__ cols,       // [E]
    float*       __restrict__ out,        // [N_ENT, 128]
    int n_edges)
{
    const int row = blockIdx.x;
    const int t   = threadIdx.x;          // 0..127, owns element t
    float* orow = out + (size_t)row * EMBED_DIM;

    if (degrees[row] > SPARSE_THRESHOLD) {
        orow[t] = 0.0f;                   // d_out is poisoned; must write zeros
        return;
    }

    // lower_bound(rows, row)
    int lo = 0, hi = n_edges;
    while (lo < hi) {
        int mid = (lo + hi) >> 1;
        if (rows[mid] < row) lo = mid + 1; else hi = mid;
    }
    const int start = lo;
    // upper_bound(rows, row)
    hi = n_edges;
    while (lo < hi) {
        int mid = (lo + hi) >> 1;
        if (rows[mid] <= row) lo = mid + 1; else hi = mid;
    }
    const int end = lo;

    float acc = 0.0f;
    int e = start;
    // Unroll by 4: independent gathers in flight, single acc chain.
    for (; e + 3 < end; e += 4) {
        int c0 = cols[e + 0];
        int c1 = cols[e + 1];
        int c2 = cols[e + 2];
        int c3 = cols[e + 3];
        float v0 = embeds[(size_t)c0 * EMBED_DIM + t];
        float v1 = embeds[(size_t)c1 * EMBED_DIM + t];
        float v2 = embeds[(size_t)c2 * EMBED_DIM + t];
        float v3 = embeds[(size_t)c3 * EMBED_DIM + t];
        acc += v0; acc += v1; acc += v2; acc += v3;
    }
    for (; e < end; ++e) {
        int c = cols[e];
        acc += embeds[(size_t)c * EMBED_DIM + t];
    }

    const int cnt = end - start;
    const float inv = 1.0f / (float)(cnt > 0 ? cnt : 1);
    orow[t] = acc * inv;
}

extern "C" void kernel_launch(void* const* d_in, const int* in_sizes, int n_in,
                              void* d_out, int out_size, void* d_ws, size_t ws_size,
                              hipStream_t stream) {
    const float* embeds  = (const float*)d_in[0];
    const int*   degrees = (const int*)d_in[1];
    const int*   rows    = (const int*)d_in[2];
    const int*   cols    = (const int*)d_in[3];
    float* out = (float*)d_out;
    const int n_edges = in_sizes[2];

    path_agg_kernel<<<N_ENT, EMBED_DIM, 0, stream>>>(
        embeds, degrees, rows, cols, out, n_edges);
}

// Round 2
// 155.603 us; speedup vs baseline: 1.2320x; 1.2320x over previous
//
#include <hip/hip_runtime.h>

#define N_ENT 100000
#define EMBED_DIM 128
#define SPARSE_THRESHOLD 5
#define ROWS_PER_BLOCK 8     // 256 threads / 32 threads-per-row

// ---------------------------------------------------------------------------
// Kernel 1: segment-boundary fill. path_rows is sorted ascending, so
// lower_bound(rows, r) == e for every r in (rows[e-1], rows[e]]. Each edge
// fills its gap; the last edge fills the tail up to N_ENT. Replaces the
// per-row binary search (44 dependent global loads) with 2 independent loads.
// ---------------------------------------------------------------------------
__global__ void seg_bounds_kernel(const int* __restrict__ rows,
                                  int* __restrict__ row_start,
                                  int n_edges) {
    int e = blockIdx.x * blockDim.x + threadIdx.x;
    const int stride = gridDim.x * blockDim.x;
    for (; e < n_edges; e += stride) {
        const int r  = rows[e];
        const int rp = (e == 0) ? -1 : rows[e - 1];
        for (int q = rp + 1; q <= r; ++q) row_start[q] = e;
        if (e == n_edges - 1) {
            for (int q = r + 1; q <= N_ENT; ++q) row_start[q] = n_edges;
        }
    }
}

// ---------------------------------------------------------------------------
// Kernel 2: aggregation. 32 threads per row, float4 per thread (128 floats).
// 8 rows per 256-thread block. Dense rows (deg > 5) write zeros and exit.
// Accumulation is strictly in edge order (matched reference bit-exact in R1).
// ---------------------------------------------------------------------------
__global__ __launch_bounds__(256) void path_agg_kernel(
    const float4* __restrict__ embeds4,   // [N_ENT * 32]
    const int*    __restrict__ degrees,   // [N_ENT]
    const int*    __restrict__ row_start, // [N_ENT + 1]
    const int*    __restrict__ cols,      // [E]
    float4*       __restrict__ out4)      // [N_ENT * 32]
{
    const int sub  = threadIdx.x >> 5;    // row within block, 0..7
    const int lane = threadIdx.x & 31;    // float4 index within row
    const int row  = blockIdx.x * ROWS_PER_BLOCK + sub;   // grid is exact

    float4* orow = out4 + (size_t)row * 32;

    if (degrees[row] > SPARSE_THRESHOLD) {
        orow[lane] = make_float4(0.f, 0.f, 0.f, 0.f);     // d_out is poisoned
        return;
    }

    const int start = row_start[row];
    const int end   = row_start[row + 1];

    float4 acc = make_float4(0.f, 0.f, 0.f, 0.f);
    int e = start;
    // 4-edge unroll: 4 independent dwordx4 gathers in flight; adds stay in
    // edge order per component so the sum order matches the reference.
    for (; e + 4 <= end; e += 4) {
        const int c0 = cols[e + 0];
        const int c1 = cols[e + 1];
        const int c2 = cols[e + 2];
        const int c3 = cols[e + 3];
        float4 v0 = embeds4[(size_t)c0 * 32 + lane];
        float4 v1 = embeds4[(size_t)c1 * 32 + lane];
        float4 v2 = embeds4[(size_t)c2 * 32 + lane];
        float4 v3 = embeds4[(size_t)c3 * 32 + lane];
        acc.x += v0.x; acc.y += v0.y; acc.z += v0.z; acc.w += v0.w;
        acc.x += v1.x; acc.y += v1.y; acc.z += v1.z; acc.w += v1.w;
        acc.x += v2.x; acc.y += v2.y; acc.z += v2.z; acc.w += v2.w;
        acc.x += v3.x; acc.y += v3.y; acc.z += v3.z; acc.w += v3.w;
    }
    for (; e < end; ++e) {
        const int c = cols[e];
        float4 v = embeds4[(size_t)c * 32 + lane];
        acc.x += v.x; acc.y += v.y; acc.z += v.z; acc.w += v.w;
    }

    const int cnt = end - start;
    const float inv = 1.0f / (float)(cnt > 0 ? cnt : 1);
    acc.x *= inv; acc.y *= inv; acc.z *= inv; acc.w *= inv;
    orow[lane] = acc;
}

// ---------------------------------------------------------------------------
// Fallback (R1 kernel): per-row binary search. Used only if ws_size is too
// small for the row_start table.
// ---------------------------------------------------------------------------
__global__ __launch_bounds__(EMBED_DIM) void path_agg_bsearch_kernel(
    const float* __restrict__ embeds,
    const int*   __restrict__ degrees,
    const int*   __restrict__ rows,
    const int*   __restrict__ cols,
    float*       __restrict__ out,
    int n_edges)
{
    const int row = blockIdx.x;
    const int t   = threadIdx.x;
    float* orow = out + (size_t)row * EMBED_DIM;

    if (degrees[row] > SPARSE_THRESHOLD) { orow[t] = 0.0f; return; }

    int lo = 0, hi = n_edges;
    while (lo < hi) { int mid = (lo + hi) >> 1; if (rows[mid] < row) lo = mid + 1; else hi = mid; }
    const int start = lo;
    hi = n_edges;
    while (lo < hi) { int mid = (lo + hi) >> 1; if (rows[mid] <= row) lo = mid + 1; else hi = mid; }
    const int end = lo;

    float acc = 0.0f;
    for (int e = start; e < end; ++e)
        acc += embeds[(size_t)cols[e] * EMBED_DIM + t];

    const int cnt = end - start;
    orow[t] = acc / (float)(cnt > 0 ? cnt : 1);
}

extern "C" void kernel_launch(void* const* d_in, const int* in_sizes, int n_in,
                              void* d_out, int out_size, void* d_ws, size_t ws_size,
                              hipStream_t stream) {
    const float* embeds  = (const float*)d_in[0];
    const int*   degrees = (const int*)d_in[1];
    const int*   rows    = (const int*)d_in[2];
    const int*   cols    = (const int*)d_in[3];
    float* out = (float*)d_out;
    const int n_edges = in_sizes[2];

    const size_t needed = (size_t)(N_ENT + 1) * sizeof(int);
    if (ws_size >= needed) {
        int* row_start = (int*)d_ws;
        seg_bounds_kernel<<<1024, 256, 0, stream>>>(rows, row_start, n_edges);
        path_agg_kernel<<<N_ENT / ROWS_PER_BLOCK, 256, 0, stream>>>(
            (const float4*)embeds, degrees, row_start, cols, (float4*)out);
    } else {
        path_agg_bsearch_kernel<<<N_ENT, EMBED_DIM, 0, stream>>>(
            embeds, degrees, rows, cols, out, n_edges);
    }
}